// Round 1
// baseline (182.987 us; speedup 1.0000x reference)
//
#include <hip/hip_runtime.h>

#define EPSF 1e-8f

__device__ __forceinline__ float minmodf(float a, float b) {
    return (a * b > 0.0f) ? (fabsf(a) < fabsf(b) ? a : b) : 0.0f;
}

// q = A * (max(A,EPS)/wp)^(2/3) * sqrt(SL)/MAN,  wp = WID + (A/WID)*s12
__device__ __forceinline__ float manning_q(float A, float WID, float invWID,
                                           float s12, float coef) {
    float h  = A * invWID;
    float wp = WID + h * s12;
    float As = fmaxf(A, EPSF);
    return A * __powf(As / wp, 0.66666667f) * coef;
}

// Green-Ampt infiltration + rain add + clamp; returns area, writes infil depth
__device__ __forceinline__ float area_from_depth(float d, float Ks, float KsF,
                                                 float pdt, float dt, float raindt,
                                                 float WID, float* infil_out) {
    float fp    = Ks + KsF * (pdt + d);          // Ks*(1 + (psi*dtheta + d)/F_safe)
    float infil = fminf(fp * dt, raindt + d);    // min(fp*dt, rain*dt + depth)
    float surf  = fmaxf(d + raindt - infil, 0.0f);
    *infil_out  = infil;
    return surf * WID;
}

__global__ __launch_bounds__(256) void plane_element_kernel(
    const float* __restrict__ depth,
    const float* __restrict__ s_rain, const float* __restrict__ s_dt,
    const float* __restrict__ s_theta, const float* __restrict__ s_F,
    const float* __restrict__ s_WID, const float* __restrict__ s_SS1,
    const float* __restrict__ s_SS2, const float* __restrict__ s_MAN,
    const float* __restrict__ s_SL, const float* __restrict__ s_dx,
    const float* __restrict__ s_Ks, const float* __restrict__ s_psi,
    const float* __restrict__ s_thetas,
    float* __restrict__ out, int N) {

    // ---- uniform scalar parameters / derived constants ----
    const float rain = *s_rain, dt = *s_dt, theta_c = *s_theta, Fc = *s_F;
    const float WID = *s_WID, SS1 = *s_SS1, SS2 = *s_SS2, MAN = *s_MAN;
    const float SL = *s_SL, dx = *s_dx, Ks = *s_Ks, psi = *s_psi, ths = *s_thetas;

    const float dtheta = fmaxf(ths - theta_c, 0.0f);
    const float F_safe = fmaxf(Fc, 1e-6f);
    const float KsF    = Ks / F_safe;
    const float pdt    = psi * dtheta;
    const float raindt = rain * dt;
    const float s12    = sqrtf(1.0f + SS1 * SS1) + sqrtf(1.0f + SS2 * SS2);
    const float coef   = sqrtf(SL) / MAN;
    const float invWID = 1.0f / WID;
    const float r      = dt / dx;          // dt/dx
    const float invN   = 1.0f / (float)N;

    float sum_infil = 0.0f;
    float maxcfl    = 0.0f;
    float dump;  // scratch infil for neighbor nodes (unused)

    const int stride = gridDim.x * blockDim.x;
    for (int i = blockIdx.x * blockDim.x + threadIdx.x; i < N; i += stride) {
        // clamped neighbor loads (out-of-range values are never used)
        const float d_im2 = depth[i >= 2 ? i - 2 : 0];
        const float d_im1 = depth[i >= 1 ? i - 1 : 0];
        const float d_i   = depth[i];
        const float d_ip1 = depth[i + 1 < N ? i + 1 : N - 1];

        float infil_i;
        const float Ai   = area_from_depth(d_i,   Ks, KsF, pdt, dt, raindt, WID, &infil_i);
        const float Aim1 = area_from_depth(d_im1, Ks, KsF, pdt, dt, raindt, WID, &dump);
        const float Aim2 = area_from_depth(d_im2, Ks, KsF, pdt, dt, raindt, WID, &dump);
        const float Aip1 = area_from_depth(d_ip1, Ks, KsF, pdt, dt, raindt, WID, &dump);

        // flux out of node i (left state at face i+1/2)
        const float slope_i = (i == 0 || i == N - 1) ? 0.0f
                              : minmodf(Ai - Aim1, Aip1 - Ai);
        const float flux_i  = manning_q(Ai + 0.5f * slope_i, WID, invWID, s12, coef);

        // flux into node i = flux out of node i-1 (0 at inlet)
        float flux_im1 = 0.0f;
        if (i > 0) {
            const float slope_m = (i == 1) ? 0.0f : minmodf(Aim1 - Aim2, Ai - Aim1);
            flux_im1 = manning_q(Aim1 + 0.5f * slope_m, WID, invWID, s12, coef);
        }

        const float An  = fmaxf(Ai - r * (flux_i - flux_im1), 0.0f);
        const float Qi  = manning_q(An, WID, invWID, s12, coef);
        const float vel = Qi / fmaxf(An, EPSF);
        const float cfl = vel * r;

        maxcfl     = fmaxf(maxcfl, cfl);
        sum_infil += infil_i;

        if (i == N - 1) out[0] = Qi;   // outflow_q
    }

    // ---- wave (64-lane) reduction ----
    for (int off = 32; off > 0; off >>= 1) {
        sum_infil += __shfl_down(sum_infil, off, 64);
        maxcfl     = fmaxf(maxcfl, __shfl_down(maxcfl, off, 64));
    }

    __shared__ float s_sum[4];
    __shared__ float s_max[4];
    const int lane = threadIdx.x & 63;
    const int wave = threadIdx.x >> 6;
    if (lane == 0) { s_sum[wave] = sum_infil; s_max[wave] = maxcfl; }
    __syncthreads();

    if (threadIdx.x == 0) {
        const float bs = s_sum[0] + s_sum[1] + s_sum[2] + s_sum[3];
        const float bm = fmaxf(fmaxf(s_max[0], s_max[1]), fmaxf(s_max[2], s_max[3]));
        const float mean_add = bs * invN;            // contribution to mean(infil_depth)
        atomicAdd(&out[2], mean_add);                // infil_depth_element
        atomicAdd(&out[1], mean_add / dt);           // infil_rate_element = depth/dt
        atomicMax((unsigned int*)&out[3], __float_as_uint(bm));  // max_cfl (>=0)
    }
}

extern "C" void kernel_launch(void* const* d_in, const int* in_sizes, int n_in,
                              void* d_out, int out_size, void* d_ws, size_t ws_size,
                              hipStream_t stream) {
    const float* depth    = (const float*)d_in[0];
    const float* s_rain   = (const float*)d_in[1];
    const float* s_dt     = (const float*)d_in[2];
    // d_in[3] = cum_rain (bookkeeping, unused by reference outputs)
    const float* s_theta  = (const float*)d_in[4];
    const float* s_F      = (const float*)d_in[5];
    const float* s_WID    = (const float*)d_in[6];
    const float* s_SS1    = (const float*)d_in[7];
    const float* s_SS2    = (const float*)d_in[8];
    const float* s_MAN    = (const float*)d_in[9];
    const float* s_SL     = (const float*)d_in[10];
    const float* s_dx     = (const float*)d_in[11];
    const float* s_Ks     = (const float*)d_in[12];
    const float* s_psi    = (const float*)d_in[13];
    const float* s_thetas = (const float*)d_in[14];

    float* out = (float*)d_out;
    const int N = in_sizes[0];

    // d_out is re-poisoned (0xAA) before every timed launch: zero accumulators.
    hipMemsetAsync(d_out, 0, out_size * sizeof(float), stream);

    const int block = 256;
    int grid = (N + block - 1) / block;
    if (grid > 2048) grid = 2048;          // 8 blocks/CU, grid-stride over nodes

    plane_element_kernel<<<grid, block, 0, stream>>>(
        depth, s_rain, s_dt, s_theta, s_F, s_WID, s_SS1, s_SS2, s_MAN,
        s_SL, s_dx, s_Ks, s_psi, s_thetas, out, N);
}

// Round 2
// 166.819 us; speedup vs baseline: 1.0969x; 1.0969x over previous
//
#include <hip/hip_runtime.h>

#define EPSF 1e-8f

__device__ __forceinline__ float minmodf(float a, float b) {
    return (a * b > 0.0f) ? (fabsf(a) < fabsf(b) ? a : b) : 0.0f;
}

// x^(2/3) for x > 0 via hardware log/exp (v_log_f32 / v_exp_f32).
__device__ __forceinline__ float pow23(float x) {
    return __expf(0.66666667f * __logf(x));
}

// q = A * (max(A,EPS)/wp)^(2/3) * sqrt(SL)/MAN,  wp = WID + (A/WID)*s12
__device__ __forceinline__ float manning_q(float A, float WID, float invWID,
                                           float s12, float coef) {
    float wp = WID + (A * invWID) * s12;
    float As = fmaxf(A, EPSF);
    return A * pow23(__fdividef(As, wp)) * coef;
}

// Green-Ampt infiltration + rain add + clamp; returns area, writes infil depth
__device__ __forceinline__ float area_from_depth(float d, float Ks, float KsF,
                                                 float pdt, float dt, float raindt,
                                                 float WID, float* infil_out) {
    float fp    = Ks + KsF * (pdt + d);          // Ks*(1 + (psi*dtheta + d)/F_safe)
    float infil = fminf(fp * dt, raindt + d);    // min(fp*dt, rain*dt + depth)
    float surf  = fmaxf(d + raindt - infil, 0.0f);
    *infil_out  = infil;
    return surf * WID;
}

__global__ __launch_bounds__(256) void plane_element_kernel(
    const float* __restrict__ depth,
    const float* __restrict__ s_rain, const float* __restrict__ s_dt,
    const float* __restrict__ s_theta, const float* __restrict__ s_F,
    const float* __restrict__ s_WID, const float* __restrict__ s_SS1,
    const float* __restrict__ s_SS2, const float* __restrict__ s_MAN,
    const float* __restrict__ s_SL, const float* __restrict__ s_dx,
    const float* __restrict__ s_Ks, const float* __restrict__ s_psi,
    const float* __restrict__ s_thetas,
    float* __restrict__ out, int N) {

    // ---- uniform scalar parameters / derived constants ----
    const float rain = *s_rain, dt = *s_dt, theta_c = *s_theta, Fc = *s_F;
    const float WID = *s_WID, SS1 = *s_SS1, SS2 = *s_SS2, MAN = *s_MAN;
    const float SL = *s_SL, dx = *s_dx, Ks = *s_Ks, psi = *s_psi, ths = *s_thetas;

    const float dtheta = fmaxf(ths - theta_c, 0.0f);
    const float F_safe = fmaxf(Fc, 1e-6f);
    const float KsF    = Ks / F_safe;
    const float pdt    = psi * dtheta;
    const float raindt = rain * dt;
    const float s12    = sqrtf(1.0f + SS1 * SS1) + sqrtf(1.0f + SS2 * SS2);
    const float coef   = sqrtf(SL) / MAN;
    const float invWID = 1.0f / WID;
    const float r      = dt / dx;
    const float invN   = 1.0f / (float)N;

    float sum_infil = 0.0f;
    float maxcfl    = 0.0f;
    float dump;

    const int nchunks = N >> 2;                 // 4 nodes per chunk
    const int stride  = gridDim.x * blockDim.x;

    for (int c = blockIdx.x * blockDim.x + threadIdx.x; c < nchunks; c += stride) {
        const int base = c << 2;

        // a[k] = area of node (base-2+k), k=0..6
        float a[7], infil[4];

        const float4 dm = *(const float4*)(depth + base);   // nodes base..base+3
        float dl0, dl1, dr;
        if (base >= 2) {
            const float2 t = *(const float2*)(depth + base - 2);
            dl0 = t.x; dl1 = t.y;
        } else {                                  // base==0 (base is mult of 4)
            dl0 = dl1 = depth[0];                 // never used (slope forced 0)
        }
        dr = (base + 4 < N) ? depth[base + 4] : 0.0f;   // unused when OOB

        a[0] = area_from_depth(dl0,  Ks, KsF, pdt, dt, raindt, WID, &dump);
        a[1] = area_from_depth(dl1,  Ks, KsF, pdt, dt, raindt, WID, &dump);
        a[2] = area_from_depth(dm.x, Ks, KsF, pdt, dt, raindt, WID, &infil[0]);
        a[3] = area_from_depth(dm.y, Ks, KsF, pdt, dt, raindt, WID, &infil[1]);
        a[4] = area_from_depth(dm.z, Ks, KsF, pdt, dt, raindt, WID, &infil[2]);
        a[5] = area_from_depth(dm.w, Ks, KsF, pdt, dt, raindt, WID, &infil[3]);
        a[6] = area_from_depth(dr,   Ks, KsF, pdt, dt, raindt, WID, &dump);

        // f[k] = outgoing flux of node m = base-1+k, k=0..4  (a-index of m is k+1)
        float f[5];
#pragma unroll
        for (int k = 0; k < 5; ++k) {
            const int m = base - 1 + k;
            const float sl = (m <= 0 || m >= N - 1)
                                 ? 0.0f
                                 : minmodf(a[k + 1] - a[k], a[k + 2] - a[k + 1]);
            const float Af = a[k + 1] + 0.5f * sl;
            f[k] = (m < 0) ? 0.0f : manning_q(Af, WID, invWID, s12, coef);
        }

        // per-node update
#pragma unroll
        for (int j = 0; j < 4; ++j) {
            const int i = base + j;
            const float fin = (i == 0) ? 0.0f : f[j];
            const float An  = fmaxf(a[j + 2] - r * (f[j + 1] - fin), 0.0f);
            const float Qi  = manning_q(An, WID, invWID, s12, coef);
            const float vel = __fdividef(Qi, fmaxf(An, EPSF));
            maxcfl          = fmaxf(maxcfl, vel * r);
            sum_infil      += infil[j];
            if (i == N - 1) out[0] = Qi;          // outflow_q
        }
    }

    // ---- wave (64-lane) reduction ----
    for (int off = 32; off > 0; off >>= 1) {
        sum_infil += __shfl_down(sum_infil, off, 64);
        maxcfl     = fmaxf(maxcfl, __shfl_down(maxcfl, off, 64));
    }

    __shared__ float s_sum[4];
    __shared__ float s_max[4];
    const int lane = threadIdx.x & 63;
    const int wave = threadIdx.x >> 6;
    if (lane == 0) { s_sum[wave] = sum_infil; s_max[wave] = maxcfl; }
    __syncthreads();

    if (threadIdx.x == 0) {
        const float bs = s_sum[0] + s_sum[1] + s_sum[2] + s_sum[3];
        const float bm = fmaxf(fmaxf(s_max[0], s_max[1]), fmaxf(s_max[2], s_max[3]));
        const float mean_add = bs * invN;
        atomicAdd(&out[2], mean_add);                              // infil_depth_element
        atomicAdd(&out[1], mean_add / dt);                         // infil_rate_element
        atomicMax((unsigned int*)&out[3], __float_as_uint(bm));    // max_cfl (>=0)
    }
}

extern "C" void kernel_launch(void* const* d_in, const int* in_sizes, int n_in,
                              void* d_out, int out_size, void* d_ws, size_t ws_size,
                              hipStream_t stream) {
    const float* depth    = (const float*)d_in[0];
    const float* s_rain   = (const float*)d_in[1];
    const float* s_dt     = (const float*)d_in[2];
    // d_in[3] = cum_rain (bookkeeping, unused by reference outputs)
    const float* s_theta  = (const float*)d_in[4];
    const float* s_F      = (const float*)d_in[5];
    const float* s_WID    = (const float*)d_in[6];
    const float* s_SS1    = (const float*)d_in[7];
    const float* s_SS2    = (const float*)d_in[8];
    const float* s_MAN    = (const float*)d_in[9];
    const float* s_SL     = (const float*)d_in[10];
    const float* s_dx     = (const float*)d_in[11];
    const float* s_Ks     = (const float*)d_in[12];
    const float* s_psi    = (const float*)d_in[13];
    const float* s_thetas = (const float*)d_in[14];

    float* out = (float*)d_out;
    const int N = in_sizes[0];

    // d_out is re-poisoned (0xAA) before every timed launch: zero accumulators.
    hipMemsetAsync(d_out, 0, out_size * sizeof(float), stream);

    const int block = 256;
    int grid = ((N >> 2) + block - 1) / block;
    if (grid > 2048) grid = 2048;          // grid-stride over 4-node chunks

    plane_element_kernel<<<grid, block, 0, stream>>>(
        depth, s_rain, s_dt, s_theta, s_F, s_WID, s_SS1, s_SS2, s_MAN,
        s_SL, s_dx, s_Ks, s_psi, s_thetas, out, N);
}

// Round 3
// 107.172 us; speedup vs baseline: 1.7074x; 1.5566x over previous
//
#include <hip/hip_runtime.h>

#define EPSF 1e-8f

__device__ __forceinline__ float minmodf(float a, float b) {
    return (a * b > 0.0f) ? (fabsf(a) < fabsf(b) ? a : b) : 0.0f;
}

// x^(2/3) for x > 0 via hardware log/exp (v_log_f32 / v_exp_f32).
__device__ __forceinline__ float pow23(float x) {
    return __expf(0.66666667f * __logf(x));
}

// q = A * (max(A,EPS)/wp)^(2/3) * sqrt(SL)/MAN,  wp = WID + (A/WID)*s12
__device__ __forceinline__ float manning_q(float A, float WID, float invWID,
                                           float s12, float coef) {
    float wp = WID + (A * invWID) * s12;
    float As = fmaxf(A, EPSF);
    return A * pow23(__fdividef(As, wp)) * coef;
}

// Green-Ampt infiltration + rain add + clamp; returns area, writes infil depth
__device__ __forceinline__ float area_from_depth(float d, float Ks, float KsF,
                                                 float pdt, float dt, float raindt,
                                                 float WID, float* infil_out) {
    float fp    = Ks + KsF * (pdt + d);          // Ks*(1 + (psi*dtheta + d)/F_safe)
    float infil = fminf(fp * dt, raindt + d);    // min(fp*dt, rain*dt + depth)
    float surf  = fmaxf(d + raindt - infil, 0.0f);
    *infil_out  = infil;
    return surf * WID;
}

__global__ __launch_bounds__(256) void plane_element_kernel(
    const float* __restrict__ depth,
    const float* __restrict__ s_rain, const float* __restrict__ s_dt,
    const float* __restrict__ s_theta, const float* __restrict__ s_F,
    const float* __restrict__ s_WID, const float* __restrict__ s_SS1,
    const float* __restrict__ s_SS2, const float* __restrict__ s_MAN,
    const float* __restrict__ s_SL, const float* __restrict__ s_dx,
    const float* __restrict__ s_Ks, const float* __restrict__ s_psi,
    const float* __restrict__ s_thetas,
    float* __restrict__ out,
    float* __restrict__ ws_sum, float* __restrict__ ws_max, int N) {

    // ---- uniform scalar parameters / derived constants ----
    const float rain = *s_rain, dt = *s_dt, theta_c = *s_theta, Fc = *s_F;
    const float WID = *s_WID, SS1 = *s_SS1, SS2 = *s_SS2, MAN = *s_MAN;
    const float SL = *s_SL, dx = *s_dx, Ks = *s_Ks, psi = *s_psi, ths = *s_thetas;

    const float dtheta = fmaxf(ths - theta_c, 0.0f);
    const float F_safe = fmaxf(Fc, 1e-6f);
    const float KsF    = Ks / F_safe;
    const float pdt    = psi * dtheta;
    const float raindt = rain * dt;
    const float s12    = sqrtf(1.0f + SS1 * SS1) + sqrtf(1.0f + SS2 * SS2);
    const float coef   = sqrtf(SL) / MAN;
    const float invWID = 1.0f / WID;
    const float r      = dt / dx;

    float sum_infil = 0.0f;
    float maxcfl    = 0.0f;
    float dump;

    const int nchunks = N >> 2;                 // 4 nodes per chunk
    const int stride  = gridDim.x * blockDim.x;

    for (int c = blockIdx.x * blockDim.x + threadIdx.x; c < nchunks; c += stride) {
        const int base = c << 2;

        // a[k] = area of node (base-2+k), k=0..6
        float a[7], infil[4];

        const float4 dm = *(const float4*)(depth + base);   // nodes base..base+3
        float dl0, dl1, dr;
        if (base >= 2) {
            const float2 t = *(const float2*)(depth + base - 2);
            dl0 = t.x; dl1 = t.y;
        } else {                                  // base==0 (base is mult of 4)
            dl0 = dl1 = depth[0];                 // never used (slope forced 0)
        }
        dr = (base + 4 < N) ? depth[base + 4] : 0.0f;   // unused when OOB

        a[0] = area_from_depth(dl0,  Ks, KsF, pdt, dt, raindt, WID, &dump);
        a[1] = area_from_depth(dl1,  Ks, KsF, pdt, dt, raindt, WID, &dump);
        a[2] = area_from_depth(dm.x, Ks, KsF, pdt, dt, raindt, WID, &infil[0]);
        a[3] = area_from_depth(dm.y, Ks, KsF, pdt, dt, raindt, WID, &infil[1]);
        a[4] = area_from_depth(dm.z, Ks, KsF, pdt, dt, raindt, WID, &infil[2]);
        a[5] = area_from_depth(dm.w, Ks, KsF, pdt, dt, raindt, WID, &infil[3]);
        a[6] = area_from_depth(dr,   Ks, KsF, pdt, dt, raindt, WID, &dump);

        // f[k] = outgoing flux of node m = base-1+k, k=0..4  (a-index of m is k+1)
        float f[5];
#pragma unroll
        for (int k = 0; k < 5; ++k) {
            const int m = base - 1 + k;
            const float sl = (m <= 0 || m >= N - 1)
                                 ? 0.0f
                                 : minmodf(a[k + 1] - a[k], a[k + 2] - a[k + 1]);
            const float Af = a[k + 1] + 0.5f * sl;
            f[k] = (m < 0) ? 0.0f : manning_q(Af, WID, invWID, s12, coef);
        }

        // per-node update
#pragma unroll
        for (int j = 0; j < 4; ++j) {
            const int i = base + j;
            const float fin = (i == 0) ? 0.0f : f[j];
            const float An  = fmaxf(a[j + 2] - r * (f[j + 1] - fin), 0.0f);
            const float Qi  = manning_q(An, WID, invWID, s12, coef);
            const float vel = __fdividef(Qi, fmaxf(An, EPSF));
            maxcfl          = fmaxf(maxcfl, vel * r);
            sum_infil      += infil[j];
            if (i == N - 1) out[0] = Qi;          // outflow_q (unique thread)
        }
    }

    // ---- wave (64-lane) reduction ----
    for (int off = 32; off > 0; off >>= 1) {
        sum_infil += __shfl_down(sum_infil, off, 64);
        maxcfl     = fmaxf(maxcfl, __shfl_down(maxcfl, off, 64));
    }

    __shared__ float s_sum[4];
    __shared__ float s_max[4];
    const int lane = threadIdx.x & 63;
    const int wave = threadIdx.x >> 6;
    if (lane == 0) { s_sum[wave] = sum_infil; s_max[wave] = maxcfl; }
    __syncthreads();

    if (threadIdx.x == 0) {
        // per-block partials: plain coalesced stores, no atomic contention
        ws_sum[blockIdx.x] = s_sum[0] + s_sum[1] + s_sum[2] + s_sum[3];
        ws_max[blockIdx.x] = fmaxf(fmaxf(s_max[0], s_max[1]),
                                   fmaxf(s_max[2], s_max[3]));
    }
}

__global__ __launch_bounds__(256) void reduce_kernel(
    const float* __restrict__ ws_sum, const float* __restrict__ ws_max,
    const float* __restrict__ s_dt, float* __restrict__ out,
    int nparts, int N) {

    float sum = 0.0f, mx = 0.0f;
    for (int i = threadIdx.x; i < nparts; i += 256) {
        sum += ws_sum[i];
        mx   = fmaxf(mx, ws_max[i]);
    }

    for (int off = 32; off > 0; off >>= 1) {
        sum += __shfl_down(sum, off, 64);
        mx   = fmaxf(mx, __shfl_down(mx, off, 64));
    }

    __shared__ float s_sum[4];
    __shared__ float s_max[4];
    const int lane = threadIdx.x & 63;
    const int wave = threadIdx.x >> 6;
    if (lane == 0) { s_sum[wave] = sum; s_max[wave] = mx; }
    __syncthreads();

    if (threadIdx.x == 0) {
        const float dt   = *s_dt;
        const float mean = (s_sum[0] + s_sum[1] + s_sum[2] + s_sum[3]) / (float)N;
        out[2] = mean;                 // infil_depth_element
        out[1] = mean / dt;            // infil_rate_element
        out[3] = fmaxf(fmaxf(s_max[0], s_max[1]), fmaxf(s_max[2], s_max[3]));
    }
}

extern "C" void kernel_launch(void* const* d_in, const int* in_sizes, int n_in,
                              void* d_out, int out_size, void* d_ws, size_t ws_size,
                              hipStream_t stream) {
    const float* depth    = (const float*)d_in[0];
    const float* s_rain   = (const float*)d_in[1];
    const float* s_dt     = (const float*)d_in[2];
    // d_in[3] = cum_rain (bookkeeping, unused by reference outputs)
    const float* s_theta  = (const float*)d_in[4];
    const float* s_F      = (const float*)d_in[5];
    const float* s_WID    = (const float*)d_in[6];
    const float* s_SS1    = (const float*)d_in[7];
    const float* s_SS2    = (const float*)d_in[8];
    const float* s_MAN    = (const float*)d_in[9];
    const float* s_SL     = (const float*)d_in[10];
    const float* s_dx     = (const float*)d_in[11];
    const float* s_Ks     = (const float*)d_in[12];
    const float* s_psi    = (const float*)d_in[13];
    const float* s_thetas = (const float*)d_in[14];

    float* out = (float*)d_out;
    const int N = in_sizes[0];

    const int block = 256;
    int grid = ((N >> 2) + block - 1) / block;
    if (grid > 2048) grid = 2048;          // grid-stride over 4-node chunks

    float* ws_sum = (float*)d_ws;          // grid floats
    float* ws_max = ws_sum + grid;         // grid floats

    plane_element_kernel<<<grid, block, 0, stream>>>(
        depth, s_rain, s_dt, s_theta, s_F, s_WID, s_SS1, s_SS2, s_MAN,
        s_SL, s_dx, s_Ks, s_psi, s_thetas, out, ws_sum, ws_max, N);

    reduce_kernel<<<1, block, 0, stream>>>(ws_sum, ws_max, s_dt, out, grid, N);
}

// Round 4
// 100.866 us; speedup vs baseline: 1.8142x; 1.0625x over previous
//
#include <hip/hip_runtime.h>

#define EPSF 1e-8f

__device__ __forceinline__ float minmodf(float a, float b) {
    return (a * b > 0.0f) ? (fabsf(a) < fabsf(b) ? a : b) : 0.0f;
}

// x^(2/3) for x > 0 via hardware log/exp (v_log_f32 / v_exp_f32).
__device__ __forceinline__ float pow23(float x) {
    return __expf(0.66666667f * __logf(x));
}

// q = A * (max(A,EPS)/wp)^(2/3) * sqrt(SL)/MAN,  wp = WID + (A/WID)*s12
__device__ __forceinline__ float manning_q(float A, float WID, float invWID,
                                           float s12, float coef) {
    float wp = WID + (A * invWID) * s12;
    float As = fmaxf(A, EPSF);
    return A * pow23(__fdividef(As, wp)) * coef;
}

// Green-Ampt infiltration + rain add + clamp; area out, infil via pointer.
__device__ __forceinline__ float area_from_depth(float d, float Ks, float KsF,
                                                 float pdt, float dt, float raindt,
                                                 float WID, float* infil_out) {
    float fp    = Ks + KsF * (pdt + d);          // Ks*(1 + (psi*dtheta + d)/F_safe)
    float infil = fminf(fp * dt, raindt + d);    // min(fp*dt, rain*dt + depth)
    float surf  = fmaxf(d + raindt - infil, 0.0f);
    *infil_out  = infil;
    return surf * WID;
}

// 8 nodes per thread, sliding 3-area window + carried upstream flux.
// Assumes N % 8 == 0 (N = 2^22 here).
__global__ __launch_bounds__(256) void plane_element_kernel(
    const float* __restrict__ depth,
    const float* __restrict__ s_rain, const float* __restrict__ s_dt,
    const float* __restrict__ s_theta, const float* __restrict__ s_F,
    const float* __restrict__ s_WID, const float* __restrict__ s_SS1,
    const float* __restrict__ s_SS2, const float* __restrict__ s_MAN,
    const float* __restrict__ s_SL, const float* __restrict__ s_dx,
    const float* __restrict__ s_Ks, const float* __restrict__ s_psi,
    const float* __restrict__ s_thetas,
    float* __restrict__ out,
    float* __restrict__ ws_sum, float* __restrict__ ws_max, int N) {

    // ---- uniform scalar parameters / derived constants ----
    const float rain = *s_rain, dt = *s_dt, theta_c = *s_theta, Fc = *s_F;
    const float WID = *s_WID, SS1 = *s_SS1, SS2 = *s_SS2, MAN = *s_MAN;
    const float SL = *s_SL, dx = *s_dx, Ks = *s_Ks, psi = *s_psi, ths = *s_thetas;

    const float dtheta = fmaxf(ths - theta_c, 0.0f);
    const float F_safe = fmaxf(Fc, 1e-6f);
    const float KsF    = Ks / F_safe;
    const float pdt    = psi * dtheta;
    const float raindt = rain * dt;
    const float s12    = sqrtf(1.0f + SS1 * SS1) + sqrtf(1.0f + SS2 * SS2);
    const float coef   = sqrtf(SL) / MAN;
    const float invWID = 1.0f / WID;
    const float r      = dt / dx;

    float sum_infil = 0.0f;
    float maxcfl    = 0.0f;
    float infil, dump;

    const int nchunks = N >> 3;                 // 8 nodes per chunk
    const int stride  = gridDim.x * blockDim.x;

    for (int c = blockIdx.x * blockDim.x + threadIdx.x; c < nchunks; c += stride) {
        const int base = c << 3;

        // d[k] = depth[base-2+k], k=0..10  (halo-2 .. halo+1)
        float d[11];
        if (base >= 2) {
            const float2 t = *(const float2*)(depth + base - 2);
            d[0] = t.x; d[1] = t.y;
        } else {
            d[0] = d[1] = depth[0];             // base==0: values never used
        }
        const float4 m0 = *(const float4*)(depth + base);
        const float4 m1 = *(const float4*)(depth + base + 4);
        d[2] = m0.x; d[3] = m0.y; d[4] = m0.z; d[5] = m0.w;
        d[6] = m1.x; d[7] = m1.y; d[8] = m1.z; d[9] = m1.w;
        d[10] = (base + 8 < N) ? depth[base + 8] : 0.0f;   // unused when OOB

        // sliding window: areas of nodes base-1, base (halo node base-2 only
        // feeds the startup flux's minmod)
        const float a_m2 = area_from_depth(d[0], Ks, KsF, pdt, dt, raindt, WID, &dump);
        float a_im1      = area_from_depth(d[1], Ks, KsF, pdt, dt, raindt, WID, &dump);
        float a_i        = area_from_depth(d[2], Ks, KsF, pdt, dt, raindt, WID, &infil);
        sum_infil += infil;                      // node base is owned

        // carried upstream flux = outgoing flux of node base-1
        float f_prev = 0.0f;
        if (base > 0) {                          // base>=8 -> node base-1 is interior
            const float sl = minmodf(a_im1 - a_m2, a_i - a_im1);
            f_prev = manning_q(a_im1 + 0.5f * sl, WID, invWID, s12, coef);
        }

#pragma unroll
        for (int j = 0; j < 8; ++j) {
            const int i = base + j;
            const float a_ip1 =
                area_from_depth(d[3 + j], Ks, KsF, pdt, dt, raindt, WID, &infil);
            if (j < 7) sum_infil += infil;       // node i+1 owned except halo j==7

            const float sl = (i == 0 || i == N - 1)
                                 ? 0.0f
                                 : minmodf(a_i - a_im1, a_ip1 - a_i);
            const float flux_i = manning_q(a_i + 0.5f * sl, WID, invWID, s12, coef);
            const float fin    = (i == 0) ? 0.0f : f_prev;

            const float An  = fmaxf(a_i - r * (flux_i - fin), 0.0f);
            const float Qi  = manning_q(An, WID, invWID, s12, coef);
            const float vel = __fdividef(Qi, fmaxf(An, EPSF));
            maxcfl          = fmaxf(maxcfl, vel * r);

            if (i == N - 1) out[0] = Qi;         // outflow_q (unique thread)

            f_prev = flux_i;
            a_im1  = a_i;
            a_i    = a_ip1;
        }
    }

    // ---- wave (64-lane) reduction ----
    for (int off = 32; off > 0; off >>= 1) {
        sum_infil += __shfl_down(sum_infil, off, 64);
        maxcfl     = fmaxf(maxcfl, __shfl_down(maxcfl, off, 64));
    }

    __shared__ float s_sum[4];
    __shared__ float s_max[4];
    const int lane = threadIdx.x & 63;
    const int wave = threadIdx.x >> 6;
    if (lane == 0) { s_sum[wave] = sum_infil; s_max[wave] = maxcfl; }
    __syncthreads();

    if (threadIdx.x == 0) {
        // per-block partials: plain coalesced stores, no atomic contention
        ws_sum[blockIdx.x] = s_sum[0] + s_sum[1] + s_sum[2] + s_sum[3];
        ws_max[blockIdx.x] = fmaxf(fmaxf(s_max[0], s_max[1]),
                                   fmaxf(s_max[2], s_max[3]));
    }
}

__global__ __launch_bounds__(256) void reduce_kernel(
    const float* __restrict__ ws_sum, const float* __restrict__ ws_max,
    const float* __restrict__ s_dt, float* __restrict__ out,
    int nparts, int N) {

    float sum = 0.0f, mx = 0.0f;
    for (int i = threadIdx.x; i < nparts; i += 256) {
        sum += ws_sum[i];
        mx   = fmaxf(mx, ws_max[i]);
    }

    for (int off = 32; off > 0; off >>= 1) {
        sum += __shfl_down(sum, off, 64);
        mx   = fmaxf(mx, __shfl_down(mx, off, 64));
    }

    __shared__ float s_sum[4];
    __shared__ float s_max[4];
    const int lane = threadIdx.x & 63;
    const int wave = threadIdx.x >> 6;
    if (lane == 0) { s_sum[wave] = sum; s_max[wave] = mx; }
    __syncthreads();

    if (threadIdx.x == 0) {
        const float dt   = *s_dt;
        const float mean = (s_sum[0] + s_sum[1] + s_sum[2] + s_sum[3]) / (float)N;
        out[2] = mean;                 // infil_depth_element
        out[1] = mean / dt;            // infil_rate_element
        out[3] = fmaxf(fmaxf(s_max[0], s_max[1]), fmaxf(s_max[2], s_max[3]));
    }
}

extern "C" void kernel_launch(void* const* d_in, const int* in_sizes, int n_in,
                              void* d_out, int out_size, void* d_ws, size_t ws_size,
                              hipStream_t stream) {
    const float* depth    = (const float*)d_in[0];
    const float* s_rain   = (const float*)d_in[1];
    const float* s_dt     = (const float*)d_in[2];
    // d_in[3] = cum_rain (bookkeeping, unused by reference outputs)
    const float* s_theta  = (const float*)d_in[4];
    const float* s_F      = (const float*)d_in[5];
    const float* s_WID    = (const float*)d_in[6];
    const float* s_SS1    = (const float*)d_in[7];
    const float* s_SS2    = (const float*)d_in[8];
    const float* s_MAN    = (const float*)d_in[9];
    const float* s_SL     = (const float*)d_in[10];
    const float* s_dx     = (const float*)d_in[11];
    const float* s_Ks     = (const float*)d_in[12];
    const float* s_psi    = (const float*)d_in[13];
    const float* s_thetas = (const float*)d_in[14];

    float* out = (float*)d_out;
    const int N = in_sizes[0];

    const int block = 256;
    int grid = ((N >> 3) + block - 1) / block;
    if (grid > 2048) grid = 2048;          // N=2^22: exactly 1 chunk per thread

    float* ws_sum = (float*)d_ws;          // grid floats
    float* ws_max = ws_sum + grid;         // grid floats

    plane_element_kernel<<<grid, block, 0, stream>>>(
        depth, s_rain, s_dt, s_theta, s_F, s_WID, s_SS1, s_SS2, s_MAN,
        s_SL, s_dx, s_Ks, s_psi, s_thetas, out, ws_sum, ws_max, N);

    reduce_kernel<<<1, block, 0, stream>>>(ws_sum, ws_max, s_dt, out, grid, N);
}